// Round 4
// baseline (105.906 us; speedup 1.0000x reference)
//
#include <hip/hip_runtime.h>
#include <hip/hip_fp16.h>

// SE3 divergence-free vector field — v3.
//
// out_c(e) = sum_u x_src[u] * Psi[u][c](r_e), Psi = 24 smooth functions of r
// with wcut and all scale factors folded in; curl folded into the atomics.
//
// Dispatch 1 (build): LDS-staged W1/W2cols -> fp16 table T (1024 x 24, 48 B
//   rows) in ws; also packs pos+x into 64 B node records and zeros the
//   privatized output copies (no separate memset dispatch).
// Dispatch 2 (edge): stages T into 48 KB LDS (coalesced), per-edge lerp from
//   LDS, node data read as float4s from the packed records (1 line for src
//   pos+x, 1 line for dst pos), privatized atomics (blockIdx%8 ~ XCD-local).
// Dispatch 3 (reduce): float4 sum of the 8 copies into d_out.

#define THREADS 256
#define RTAB 1024
#define NCOPIES 8

// ws layout (bytes)
#define TAB_OFF   0u
#define TAB_BYTES (RTAB * 24 * 2u)            // 48 KB fp16
#define NODE_OFF  65536u                      // 64 KB aligned
#define NODE_BYTES(nNodes) ((unsigned)(nNodes) * 64u)

__global__ __launch_bounds__(THREADS) void se3_build(
    const float* __restrict__ W1,   // (10, 64)
    const float* __restrict__ W2,   // (64, 384)
    const float* __restrict__ pos,  // (nNodes, 3)
    const float* __restrict__ x,    // (nNodes, 8)
    __half*  __restrict__ T,        // (RTAB, 24)
    float4*  __restrict__ nodes,    // (nNodes, 4) float4 records
    float4*  __restrict__ copies,   // NCOPIES*outN floats, zeroed here
    int nNodes, int copies4)
{
    __shared__ float sW1[10 * 65];
    __shared__ float sW2[64 * 24];  // [k*24 + j], j = u*3+c

    for (int t = threadIdx.x; t < 640; t += THREADS) {
        int j = t >> 6, k = t & 63;
        sW1[j * 65 + k] = W1[t];
    }
    for (int t = threadIdx.x; t < 64 * 24; t += THREADS) {
        int k = t / 24, j = t - 24 * k;
        int u = j / 3, c = j - 3 * u;
        sW2[t] = W2[k * 384 + u * 32 + c];
    }
    __syncthreads();

    int g = blockIdx.x * THREADS + threadIdx.x;
    int nthreads = gridDim.x * THREADS;

    // ---- table ----
    if (g < RTAB * 24) {
        int i = g / 24;
        int j = g - i * 24;
        float r = 3.0f * (float)i / (float)(RTAB - 1);

        float psi = 0.0f;
        float t10 = 10.0f - (10.0f / 3.0f) * r;
        if (t10 > 0.0f) {
            // radial bump: at most 2 of 10 basis functions non-zero.
            // C0 = 1.14136*e^2 (sqrt(10) norms cancel between emb and W1).
            const float C0 = 8.43357306907549f;
            float q  = r * (11.0f / 3.0f);
            int   jf = (int)q;
            float da = q - (float)jf;
            float db = da - 1.0f;
            float ya = fmaxf(1.0f - da * da, 1e-7f);
            float yb = fmaxf(1.0f - db * db, 1e-7f);
            int ja = jf - 1, jb = jf;
            float ea = (ja >= 0) ? C0 * __expf(-1.0f / ya) : 0.0f;
            float eb = (jb <= 9) ? C0 * __expf(-1.0f / yb) : 0.0f;
            int jac = ja < 0 ? 0 : ja;
            int jbc = jb > 9 ? 9 : jb;
            const float* w1a = sW1 + jac * 65;
            const float* w1b = sW1 + jbc * 65;

            float acc = 0.0f;
#pragma unroll 8
            for (int k = 0; k < 64; ++k) {
                float pre = ea * w1a[k] + eb * w1b[k];
                float h   = pre * __builtin_amdgcn_rcpf(1.0f + __expf(-pre));
                acc = fmaf(h, sW2[k * 24 + j], acc);
            }
            // fold cutoff and 1/(8*sqrt(8))
            psi = acc * __expf(-1.0f / t10) * 0.04419417382415922f;
        }
        T[i * 24 + j] = __float2half(psi);
    }

    // ---- pack nodes: 64 B record = {pos.xyz,0}{x0..3}{x4..7}{pad} ----
    for (int n = g; n < nNodes; n += nthreads) {
        const float* p = pos + 3 * (size_t)n;
        const float4* xf = reinterpret_cast<const float4*>(x + 8 * (size_t)n);
        float4 rec0 = make_float4(p[0], p[1], p[2], 0.0f);
        nodes[n * 4 + 0] = rec0;
        nodes[n * 4 + 1] = xf[0];
        nodes[n * 4 + 2] = xf[1];
    }

    // ---- zero privatized copies ----
    float4 z = make_float4(0.f, 0.f, 0.f, 0.f);
    for (int i = g; i < copies4; i += nthreads) copies[i] = z;
}

__global__ __launch_bounds__(THREADS) void se3_edge(
    const float4* __restrict__ nodes,  // packed records
    const int*    __restrict__ esrc,
    const int*    __restrict__ edst,
    const float4* __restrict__ Tg,     // table as float4 (3072 of them)
    float*        __restrict__ outbuf, // ncopies x outN, zeroed
    int E, int ncopies, int outN)
{
    __shared__ __align__(16) __half sT[RTAB * 24];   // 48 KB

    float4* sT4 = reinterpret_cast<float4*>(sT);
#pragma unroll
    for (int q = 0; q < (RTAB * 24 * 2 / 16) / THREADS; ++q)
        sT4[threadIdx.x + q * THREADS] = Tg[threadIdx.x + q * THREADS];
    __syncthreads();

    int e = blockIdx.x * THREADS + threadIdx.x;
    if (e >= E) return;

    int s = esrc[e];
    int d = edst[e];

    float4 ps = nodes[s * 4 + 0];
    float4 xA = nodes[s * 4 + 1];
    float4 xB = nodes[s * 4 + 2];
    float4 pd = nodes[d * 4 + 0];

    float ex = ps.x - pd.x, ey = ps.y - pd.y, ez = ps.z - pd.z;
    float r  = sqrtf(ex * ex + ey * ey + ez * ez + 1e-18f);
    if (r >= 3.0f) return;   // wcut == 0

    float tq = r * ((float)(RTAB - 1) / 3.0f);
    int   i  = (int)tq;
    if (i > RTAB - 2) i = RTAB - 2;
    float f  = tq - (float)i;

    float xs[8] = {xA.x, xA.y, xA.z, xA.w, xB.x, xB.y, xB.z, xB.w};
    float p0 = 0.f, p1 = 0.f, p2 = 0.f;

    // rows i, i+1: 24 halves each, 8 B aligned -> 6 uint2 reads per row
    const uint2* row_a = reinterpret_cast<const uint2*>(sT + i * 24);
    const uint2* row_b = reinterpret_cast<const uint2*>(sT + (i + 1) * 24);
#pragma unroll
    for (int m = 0; m < 6; ++m) {
        union { uint2 u; __half2 h[2]; } A, B;
        A.u = row_a[m];
        B.u = row_b[m];
        float2 a0 = __half22float2(A.h[0]), a1 = __half22float2(A.h[1]);
        float2 b0 = __half22float2(B.h[0]), b1 = __half22float2(B.h[1]);
        // j = 4m + {0,1,2,3};  j = u*3 + c  (u = j/3, c = j%3) — compile-time
        {
            const int j = 4 * m + 0, u = j / 3, c = j - 3 * u;
            float v = fmaf(f, b0.x - a0.x, a0.x);
            if (c == 0) p0 = fmaf(xs[u], v, p0);
            else if (c == 1) p1 = fmaf(xs[u], v, p1);
            else p2 = fmaf(xs[u], v, p2);
        }
        {
            const int j = 4 * m + 1, u = j / 3, c = j - 3 * u;
            float v = fmaf(f, b0.y - a0.y, a0.y);
            if (c == 0) p0 = fmaf(xs[u], v, p0);
            else if (c == 1) p1 = fmaf(xs[u], v, p1);
            else p2 = fmaf(xs[u], v, p2);
        }
        {
            const int j = 4 * m + 2, u = j / 3, c = j - 3 * u;
            float v = fmaf(f, b1.x - a1.x, a1.x);
            if (c == 0) p0 = fmaf(xs[u], v, p0);
            else if (c == 1) p1 = fmaf(xs[u], v, p1);
            else p2 = fmaf(xs[u], v, p2);
        }
        {
            const int j = 4 * m + 3, u = j / 3, c = j - 3 * u;
            float v = fmaf(f, b1.y - a1.y, a1.y);
            if (c == 0) p0 = fmaf(xs[u], v, p0);
            else if (c == 1) p1 = fmaf(xs[u], v, p1);
            else p2 = fmaf(xs[u], v, p2);
        }
    }

    // curl folded in: (psi2-psi1, psi0-psi2, psi1-psi0)
    float* ob = outbuf + (size_t)(blockIdx.x % ncopies) * outN + 3 * d;
    atomicAdd(ob + 0, p2 - p1);
    atomicAdd(ob + 1, p0 - p2);
    atomicAdd(ob + 2, p1 - p0);
}

__global__ __launch_bounds__(THREADS) void se3_reduce(
    const float4* __restrict__ ws, float4* __restrict__ out,
    int outN4, int ncopies)
{
    int idx = blockIdx.x * THREADS + threadIdx.x;
    if (idx >= outN4) return;
    float4 acc = ws[idx];
    for (int c = 1; c < ncopies; ++c) {
        float4 v = ws[(size_t)c * outN4 + idx];
        acc.x += v.x; acc.y += v.y; acc.z += v.z; acc.w += v.w;
    }
    out[idx] = acc;
}

extern "C" void kernel_launch(void* const* d_in, const int* in_sizes, int n_in,
                              void* d_out, int out_size, void* d_ws, size_t ws_size,
                              hipStream_t stream) {
    const float* x    = (const float*)d_in[0];
    const float* pos  = (const float*)d_in[1];
    const int*   esrc = (const int*)d_in[2];
    const int*   edst = (const int*)d_in[3];
    const float* W1   = (const float*)d_in[4];
    const float* W2   = (const float*)d_in[5];

    int E      = in_sizes[2];
    int outN   = out_size;              // B*N*3
    int nNodes = in_sizes[1] / 3;       // B*N

    char* ws = (char*)d_ws;
    __half* T      = (__half*)(ws + TAB_OFF);
    float4* nodes  = (float4*)(ws + NODE_OFF);
    size_t  copOff = (size_t)NODE_OFF + NODE_BYTES(nNodes);
    float*  copies = (float*)(ws + copOff);

    size_t need = copOff + (size_t)NCOPIES * outN * sizeof(float);
    int ncopies = (ws_size >= need) ? NCOPIES : 1;
    if (ncopies == 1) {
        // fallback: atomics straight into d_out
        copies = (float*)d_out;
        hipMemsetAsync(d_out, 0, (size_t)outN * sizeof(float), stream);
    }

    int copies4 = (ncopies == 1) ? 0 : (ncopies * outN) / 4;
    int buildBlocks = (nNodes + THREADS - 1) / THREADS;   // >= RTAB*24/THREADS
    se3_build<<<buildBlocks, THREADS, 0, stream>>>(
        W1, W2, pos, x, T, nodes, (float4*)copies, nNodes, copies4);

    int edgeBlocks = (E + THREADS - 1) / THREADS;
    se3_edge<<<edgeBlocks, THREADS, 0, stream>>>(
        nodes, esrc, edst, (const float4*)T, copies, E, ncopies, outN);

    if (ncopies > 1) {
        int outN4 = outN / 4;
        se3_reduce<<<(outN4 + THREADS - 1) / THREADS, THREADS, 0, stream>>>(
            (const float4*)copies, (float4*)d_out, outN4, ncopies);
    }
}